// Round 1
// baseline (570.310 us; speedup 1.0000x reference)
//
#include <hip/hip_runtime.h>
#include <hip/hip_bf16.h>
#include <cstdint>
#include <cstddef>

typedef __bf16 bf16_t;
typedef __attribute__((ext_vector_type(8))) __bf16 bf16x8;
typedef __attribute__((ext_vector_type(4))) __bf16 bf16x4;
typedef __attribute__((ext_vector_type(4))) float floatx4;

#define BM 128
#define BN 128
#define BK 32

// ---------------------------------------------------------------- helpers
__device__ __forceinline__ void async_copy_16B(const void* g, void* l) {
  __builtin_amdgcn_global_load_lds(
      (const __attribute__((address_space(1))) void*)g,
      (__attribute__((address_space(3))) void*)l, 16, 0, 0);
}

// ---------------------------------------------------------------- casts
__global__ __launch_bounds__(256) void cast_f32_to_bf16(
    const float* __restrict__ in, bf16_t* __restrict__ out, int n) {
  const int i = (blockIdx.x * 256 + threadIdx.x) * 4;
  if (i >= n) return;
  const float4 v = *(const float4*)(in + i);
  bf16x4 o;
  o.x = (bf16_t)v.x; o.y = (bf16_t)v.y; o.z = (bf16_t)v.z; o.w = (bf16_t)v.w;
  *(bf16x4*)(out + i) = o;
}

// w_dw [4096][127] -> wt [127][4096]
__global__ __launch_bounds__(256) void transpose_w(
    const float* __restrict__ w, float* __restrict__ wt) {
  const int idx = blockIdx.x * 256 + threadIdx.x;
  if (idx >= 127 * 4096) return;
  const int j = idx >> 12;
  const int c = idx & 4095;
  wt[idx] = w[c * 127 + j];
}

// ---------------------------------------------------------------- GEMM (NT)
// C[M,N] = A[M,K] * B[N,K]^T ; A,B bf16 row-major, C = OutT row-major.
// 128x128 tile, BK=32, 4 waves each computing 64x64 via 4x4 mfma_16x16x32.
template <typename OutT>
__global__ __launch_bounds__(256) void gemm_bt(
    const bf16_t* __restrict__ A, const bf16_t* __restrict__ B,
    OutT* __restrict__ C, int M, int N, int K) {
  __shared__ bf16_t As[BM * BK];
  __shared__ bf16_t Bs[BN * BK];
  const int t = threadIdx.x;
  const int lane = t & 63;
  const int wave = t >> 6;
  const int m0 = blockIdx.y * BM;
  const int n0 = blockIdx.x * BN;
  const int wr = (wave >> 1) * 64;   // wave row offset in C tile
  const int wc = (wave & 1) * 64;    // wave col offset in C tile
  const int fr = lane & 15;          // fragment row (m or n)
  const int fk = (lane >> 4) * 8;    // fragment k offset

  floatx4 acc[4][4] = {};

  const int kTiles = K / BK;
  for (int kt = 0; kt < kTiles; ++kt) {
    const int k0 = kt * BK;
    __syncthreads();  // protect LDS from overwrite while still being read
    // stage A,B tiles: 128 rows x 32 bf16 = 8KB each; 512 16B-chunks total
#pragma unroll
    for (int it = 0; it < 2; ++it) {
      const int chunk = it * 256 + t;
      const int row = chunk >> 2;        // 4 chunks of 8 bf16 per row
      const int kc = (chunk & 3) * 8;
      async_copy_16B(A + (size_t)(m0 + row) * K + k0 + kc, As + chunk * 8);
      async_copy_16B(B + (size_t)(n0 + row) * K + k0 + kc, Bs + chunk * 8);
    }
    __syncthreads();  // drains vmcnt(0) -> staging complete

    bf16x8 af[4], bfr[4];
#pragma unroll
    for (int i = 0; i < 4; ++i) {
      af[i]  = *(const bf16x8*)(As + (wr + i * 16 + fr) * BK + fk);
      bfr[i] = *(const bf16x8*)(Bs + (wc + i * 16 + fr) * BK + fk);
    }
#pragma unroll
    for (int i = 0; i < 4; ++i)
#pragma unroll
      for (int j = 0; j < 4; ++j)
        acc[i][j] = __builtin_amdgcn_mfma_f32_16x16x32_bf16(
            af[i], bfr[j], acc[i][j], 0, 0, 0);
  }

  // C/D layout: col = lane&15, row = (lane>>4)*4 + reg
  const int cr = (lane >> 4) * 4;
  const int cc = lane & 15;
#pragma unroll
  for (int i = 0; i < 4; ++i)
#pragma unroll
    for (int j = 0; j < 4; ++j)
#pragma unroll
      for (int r = 0; r < 4; ++r) {
        const int row = m0 + wr + i * 16 + cr + r;
        const int col = n0 + wc + j * 16 + cc;
        C[(size_t)row * N + col] = (OutT)acc[i][j][r];
      }
}

// ---------------------------------------------------------------- conv+gate
// vg: [8192][8192] bf16 (v = cols 0..4095, g = cols 4096..8191)
// wt: [127][4096] fp32 transposed filters ; y: [8192][4096] bf16
// Block: 64 channels x 64 l-outputs; 4 waves, each wave 16 l's, lane=channel.
#define CROWS 190  // 64 + 126 history rows

__global__ __launch_bounds__(256) void conv_gate(
    const bf16_t* __restrict__ vg, const float* __restrict__ wt,
    const float* __restrict__ b_dw, bf16_t* __restrict__ y) {
  __shared__ bf16_t vt[CROWS * 64];
  const int t = threadIdx.x;
  const int lane = t & 63;
  const int wave = t >> 6;
  const int c0 = blockIdx.x * 64;
  const int lt = blockIdx.y & 63;
  const int b = blockIdx.y >> 6;
  const int l0 = lt * 64;

  // stage v tile rows [l0-126, l0+63] x 64 channels (zeros for l<0)
  for (int chunk = t; chunk < CROWS * 8; chunk += 256) {
    const int row = chunk >> 3;
    const int cc = (chunk & 7) * 8;
    const int l = l0 - 126 + row;
    uint4* dst = (uint4*)(vt + row * 64 + cc);
    if (l < 0) {
      *dst = make_uint4(0u, 0u, 0u, 0u);
    } else {
      *dst = *(const uint4*)(vg + (size_t)(b * 4096 + l) * 8192 + c0 + cc);
    }
  }
  __syncthreads();

  const int c = c0 + lane;
  const int lb = l0 + wave * 16;
  const float bias = b_dw[c];
  float acc[16], win[16];
#pragma unroll
  for (int i = 0; i < 16; ++i) acc[i] = bias;
  const int r0 = wave * 16;  // tile row of v[lb-126]
#pragma unroll
  for (int i = 0; i < 16; ++i) win[i] = (float)vt[(r0 + i) * 64 + lane];

  const float* wcp = wt + c;
  // tap j uses v[lb-126+j+i] = tile row r0+j+i ; window slides 1/row per tap
  for (int jo = 0; jo < 112; jo += 16) {
#pragma unroll
    for (int ji = 0; ji < 16; ++ji) {
      const int j = jo + ji;
      const float wj = wcp[(size_t)j * 4096];
#pragma unroll
      for (int i = 0; i < 16; ++i) acc[i] += wj * win[(ji + i) & 15];
      win[ji] = (float)vt[(r0 + 16 + j) * 64 + lane];
    }
  }
#pragma unroll
  for (int ji = 0; ji < 15; ++ji) {  // tail taps j = 112..126
    const int j = 112 + ji;
    const float wj = wcp[(size_t)j * 4096];
#pragma unroll
    for (int i = 0; i < 16; ++i) acc[i] += wj * win[(ji + i) & 15];
    if (ji < 14) win[ji] = (float)vt[(r0 + 16 + j) * 64 + lane];
  }

  const bf16_t* gp = vg + (size_t)(b * 4096 + lb) * 8192 + 4096 + c;
  bf16_t* yp = y + (size_t)(b * 4096 + lb) * 4096 + c;
#pragma unroll
  for (int i = 0; i < 16; ++i) {
    const float gv = (float)gp[(size_t)i * 8192];
    const float v = acc[i];
    const float sv = v / (1.f + __expf(-v));
    const float sg = gv / (1.f + __expf(-gv));
    yp[(size_t)i * 4096] = (bf16_t)(sv * sg);
  }
}

// ---------------------------------------------------------------- launch
extern "C" void kernel_launch(void* const* d_in, const int* in_sizes, int n_in,
                              void* d_out, int out_size, void* d_ws,
                              size_t ws_size, hipStream_t stream) {
  const float* x     = (const float*)d_in[0];  // [2,4096,1024]
  const float* w_in  = (const float*)d_in[1];  // [8192,1024]
  const float* w_dw  = (const float*)d_in[2];  // [4096,127]
  const float* b_dw  = (const float*)d_in[3];  // [4096]
  const float* w_out = (const float*)d_in[4];  // [1024,4096]
  float* out = (float*)d_out;                  // [2,4096,1024]

  char* p = (char*)d_ws;
  bf16_t* x_bf  = (bf16_t*)p; p += (size_t)8192 * 1024 * 2;
  bf16_t* wi_bf = (bf16_t*)p; p += (size_t)8192 * 1024 * 2;
  bf16_t* wo_bf = (bf16_t*)p; p += (size_t)1024 * 4096 * 2;
  float*  wt    = (float*)p;  p += (size_t)127 * 4096 * 4;
  bf16_t* vg    = (bf16_t*)p; p += (size_t)8192 * 8192 * 2;
  bf16_t* y     = (bf16_t*)p; p += (size_t)8192 * 4096 * 2;

  cast_f32_to_bf16<<<8192, 256, 0, stream>>>(x, x_bf, 8192 * 1024);
  cast_f32_to_bf16<<<8192, 256, 0, stream>>>(w_in, wi_bf, 8192 * 1024);
  cast_f32_to_bf16<<<4096, 256, 0, stream>>>(w_out, wo_bf, 4096 * 1024);
  transpose_w<<<2032, 256, 0, stream>>>(w_dw, wt);

  // vg[8192,8192] = x[8192,1024] @ w_in[8192,1024]^T
  gemm_bt<bf16_t><<<dim3(64, 64), 256, 0, stream>>>(x_bf, wi_bf, vg,
                                                    8192, 8192, 1024);
  // y = silu(causal_dwconv(v)+b) * silu(g)
  conv_gate<<<dim3(64, 128), 256, 0, stream>>>(vg, wt, b_dw, y);
  // out[8192,1024] = y[8192,4096] @ w_out[1024,4096]^T
  gemm_bt<float><<<dim3(8, 64), 256, 0, stream>>>(y, wo_bf, out,
                                                  8192, 1024, 4096);
}